// Round 6
// baseline (664.302 us; speedup 1.0000x reference)
//
#include <hip/hip_runtime.h>

#define NN 100000
#define NE 1600000
#define DD 128
#define CAP 56      // padded-CSR capacity; P(Poisson(16) >= 56) ~ 5e-15
#define BCAP 208896 // bucket capacity: NE/8 + ~21 sigma of Binomial(NE,1/8)
#define SBLK 128    // scatter blocks per range

// ---------- bf16 helpers (manual, RNE) ----------
static __device__ __forceinline__ unsigned short f2b(float f) {
  unsigned int x = __float_as_uint(f);
  unsigned int r = x + 0x7fffu + ((x >> 16) & 1u);
  return (unsigned short)(r >> 16);
}
static __device__ __forceinline__ float b2f(unsigned short u) {
  return __uint_as_float(((unsigned int)u) << 16);
}

typedef __attribute__((ext_vector_type(8))) short short8;
typedef __attribute__((ext_vector_type(4))) float f32x4;

union V8 {
  uint4 u4;
  short8 s8;
  unsigned short us[8];
};

// ---------- edge-index dtype detector + bucket-cursor zeroing ----------
__global__ void detect_k(const int* __restrict__ ei, int* __restrict__ flag,
                         int* __restrict__ bcur) {
  int v = ei[2 * threadIdx.x + 1];
  unsigned long long b = __ballot(v != 0);
  if (threadIdx.x == 0) *flag = (b == 0ull) ? 1 : 0;
  if (threadIdx.x < 8) bcur[threadIdx.x] = 0;
}

// ---------- fp32 -> bf16 cast (x input, row-major) ----------
__global__ __launch_bounds__(256) void cast_k(const float* __restrict__ x,
                                              unsigned short* __restrict__ x16) {
  size_t i = ((size_t)blockIdx.x * 256 + threadIdx.x) * 8;
  f32x4 a = *(const f32x4*)(x + i);
  f32x4 b = *(const f32x4*)(x + i + 4);
  V8 v;
#pragma unroll
  for (int j = 0; j < 4; ++j) {
    v.us[j] = f2b(a[j]);
    v.us[4 + j] = f2b(b[j]);
  }
  *(uint4*)(x16 + i) = v.u4;
}

// ---------- pack+bin: edges into 8 dst-range buckets (single pass) ----------
// R6: replaces the unbucketed pack + 8-pass filtered scatter. Each edge is
// written once into bucket d/(NN/8); the scatter then reads each edge once
// instead of 8x. LDS-aggregated cursors: 8 global atomics per block.
// Also zeroes cnt and the BN stat buffers (housekeeping).
__global__ __launch_bounds__(256) void pack_k(const int* __restrict__ ei,
                                              int2* __restrict__ buckets,
                                              int* __restrict__ bcur,
                                              int* __restrict__ cnt,
                                              float* __restrict__ stats,
                                              const int* __restrict__ flag) {
  __shared__ int lcnt[8];
  __shared__ int lbase[8];
  const int tid = threadIdx.x;
  if (tid < 8) lcnt[tid] = 0;
  __syncthreads();
  const int mode = *flag;
  const int gid = blockIdx.x * 256 + tid;
  int s, d;
  if (mode) {  // int64 little-endian, values < 2^31: low word at even offset
    s = ((const int2*)ei)[gid].x;
    d = ((const int2*)ei)[(size_t)NE + gid].x;
  } else {
    s = ei[gid];
    d = ei[NE + gid];
  }
  const int r = d / (NN / 8);
  const int slot = atomicAdd(&lcnt[r], 1);
  __syncthreads();
  if (tid < 8) lbase[tid] = atomicAdd(&bcur[tid], lcnt[tid]);
  __syncthreads();
  const int idx = lbase[r] + slot;
  if (idx < BCAP) buckets[(size_t)r * BCAP + idx] = make_int2(s, d);
  if (gid < NN) cnt[gid] = 0;
  if (gid < 1024) stats[gid] = 0.f;  // 4 layers x (sum[128], sumsq[128])
}

// ---------- padded-CSR scatter from buckets (each edge read ONCE) ----------
// blockIdx&7 = range r -> XCD r (round-robin heuristic); cnt/csr slice
// (2.85 MB) is L2-resident with no competing stream to evict it.
__global__ __launch_bounds__(256) void scatter_k(const int2* __restrict__ buckets,
                                                 const int* __restrict__ bcur,
                                                 int* __restrict__ cnt,
                                                 int* __restrict__ csr) {
  const int r = blockIdx.x & 7;
  const int g = blockIdx.x >> 3;
  const int nb = min(bcur[r], BCAP);
  const int2* bk = buckets + (size_t)r * BCAP;
  for (int e = g * 256 + threadIdx.x; e < nb; e += SBLK * 256) {
    int2 sd = bk[e];
    int c = atomicAdd(&cnt[sd.y], 1);
    if (c < CAP) csr[(size_t)sd.y * CAP + c] = sd.x;
  }
}

// ---------- weight prep: transpose+cast all 7 matrices to bf16 wT[n][k] ----------
__global__ __launch_bounds__(256) void wprep_k(const float* __restrict__ W1,
                                               const float* __restrict__ W2,
                                               const float* __restrict__ fW1,
                                               const float* __restrict__ fW2,
                                               unsigned short* __restrict__ wt) {
  int b = blockIdx.x;
  const float* src;
  int moff, N;
  if (b < 192) {
    int m = b >> 6;
    src = W1 + m * 16384;
    moff = m * 16384;
    N = 128;
    b &= 63;
  } else if (b < 384) {
    int m = (b - 192) >> 6;
    src = W2 + m * 16384;
    moff = (3 + m) * 16384;
    N = 128;
    b = (b - 192) & 63;
  } else if (b < 448) {
    src = fW1;
    moff = 6 * 16384;
    N = 128;
    b -= 384;
  } else {
    src = fW2;
    moff = 7 * 16384;
    N = 64;
    b -= 448;
  }
  int idx = b * 256 + threadIdx.x;  // n*128 + k
  int n = idx >> 7, k = idx & 127;
  if (n < N) wt[moff + idx] = f2b(src[(size_t)k * N + n]);
}

// ---------- gather-reduce (unchanged control): h16[node] = x16[node] + sum x16[s] ----------
// 16 threads/node, 8 cols each; unroll-4 independent accumulators.
__global__ __launch_bounds__(256) void gather_k(const int* __restrict__ cnt,
                                                const int* __restrict__ csr,
                                                const unsigned short* __restrict__ x16,
                                                unsigned short* __restrict__ h16) {
  const int node = blockIdx.x * 16 + (threadIdx.x >> 4);
  const int l = threadIdx.x & 15;
  const int beg = node * CAP;
  const int end = beg + cnt[node];
  V8 v;
  v.u4 = *(const uint4*)(x16 + (size_t)node * DD + l * 8);
  float a0[8], a1[8], a2[8], a3[8];
#pragma unroll
  for (int j = 0; j < 8; ++j) {
    a0[j] = b2f(v.us[j]);
    a1[j] = 0.f;
    a2[j] = 0.f;
    a3[j] = 0.f;
  }
  int p = beg;
  for (; p + 4 <= end; p += 4) {
    const int s0 = csr[p], s1 = csr[p + 1], s2 = csr[p + 2], s3 = csr[p + 3];
    V8 w0, w1, w2, w3;
    w0.u4 = *(const uint4*)(x16 + (size_t)s0 * DD + l * 8);
    w1.u4 = *(const uint4*)(x16 + (size_t)s1 * DD + l * 8);
    w2.u4 = *(const uint4*)(x16 + (size_t)s2 * DD + l * 8);
    w3.u4 = *(const uint4*)(x16 + (size_t)s3 * DD + l * 8);
#pragma unroll
    for (int j = 0; j < 8; ++j) {
      a0[j] += b2f(w0.us[j]);
      a1[j] += b2f(w1.us[j]);
      a2[j] += b2f(w2.us[j]);
      a3[j] += b2f(w3.us[j]);
    }
  }
  for (; p < end; ++p) {
    const int s0 = csr[p];
    V8 w0;
    w0.u4 = *(const uint4*)(x16 + (size_t)s0 * DD + l * 8);
#pragma unroll
    for (int j = 0; j < 8; ++j) a0[j] += b2f(w0.us[j]);
  }
  V8 o;
#pragma unroll
  for (int j = 0; j < 8; ++j) o.us[j] = f2b((a0[j] + a1[j]) + (a2[j] + a3[j]));
  *(uint4*)(h16 + (size_t)node * DD + l * 8) = o.u4;
}

// ---------- MFMA GEMM (R4-exact): C[M x NCOLS] = A[M x 128] @ wT^T + bias ----------
// 512 threads / 128 rows per block; A-row loads hoisted above the LDS staging
// so their latency hides under the weight prologue.
// AMODE: 1 = A bf16 plain, 2 = A bf16 with BN(scale,shift from raw stats)+ReLU
// EPI:   0 = store bf16, 1 = relu + store bf16, 2 = store fp32
// STATS: 1 = accumulate per-column sum/sumsq of the (rounded) output
template <int AMODE, int NCOLS, int EPI, int STATS>
__global__ __launch_bounds__(512) void gemm_k(const unsigned short* __restrict__ Aptr,
                                              const unsigned short* __restrict__ wT,
                                              const float* __restrict__ bias,
                                              const float* __restrict__ bn_stats,
                                              const float* __restrict__ gamma,
                                              const float* __restrict__ beta,
                                              void* __restrict__ Cptr,
                                              float* __restrict__ stats_out) {
  __shared__ unsigned short bT[NCOLS][136];  // 136: 16B-aligned rows, bank-spread
  __shared__ float biasS[NCOLS];
  __shared__ float scS[128];
  __shared__ float shS[128];
  __shared__ float sS[NCOLS];
  __shared__ float s2S[NCOLS];
  const int tid = threadIdx.x;
  const int wv = tid >> 6;
  const int lane = tid & 63;
  const int l16 = lane & 15;
  const int quad = lane >> 4;
  const int arow = blockIdx.x * 128 + wv * 16 + l16;  // A row (m = lane&15)
  const bool rv = arow < NN;

  // ---- A loads first: latency overlaps the weight staging below ----
  V8 afr[4];
#pragma unroll
  for (int kc = 0; kc < 4; ++kc) {
    if (rv) {
      afr[kc].u4 = *(const uint4*)(Aptr + (size_t)arow * DD + kc * 32 + quad * 8);
    } else {
      afr[kc].u4 = make_uint4(0u, 0u, 0u, 0u);
    }
  }

  // prologue: straight vectorized copy of pre-transposed weights
  for (int i = tid; i < NCOLS * 16; i += 512) {
    int n = i >> 4, k8 = (i & 15) << 3;
    *(uint4*)&bT[n][k8] = *(const uint4*)(wT + n * 128 + k8);
  }
  if (tid < NCOLS) biasS[tid] = bias[tid];
  if (AMODE == 2 && tid < 128) {
    const float inv_n = 1.0f / (float)NN;
    float mu = bn_stats[tid] * inv_n;
    float var = bn_stats[128 + tid] * inv_n - mu * mu;
    float sc = gamma[tid] * rsqrtf(var + 1e-5f);
    scS[tid] = sc;
    shS[tid] = beta[tid] - mu * sc;
  }
  if (STATS && tid < NCOLS) {
    sS[tid] = 0.f;
    s2S[tid] = 0.f;
  }
  __syncthreads();

  f32x4 acc[NCOLS / 16];
#pragma unroll
  for (int nt = 0; nt < NCOLS / 16; ++nt) acc[nt] = (f32x4)(0.0f);

#pragma unroll
  for (int kc = 0; kc < 4; ++kc) {
    const int k0 = kc * 32 + quad * 8;
    V8 af = afr[kc];
    if (AMODE == 2) {
#pragma unroll
      for (int j = 0; j < 8; ++j) {
        float f = fmaf(b2f(af.us[j]), scS[k0 + j], shS[k0 + j]);
        af.us[j] = f2b(fmaxf(f, 0.0f));
      }
    }
#pragma unroll
    for (int nt = 0; nt < NCOLS / 16; ++nt) {
      V8 bf;
      bf.u4 = *(const uint4*)&bT[nt * 16 + l16][k0];
      acc[nt] = __builtin_amdgcn_mfma_f32_16x16x32_bf16(af.s8, bf.s8, acc[nt], 0, 0, 0);
    }
  }

  // C/D layout: col = lane&15, row = quad*4 + reg
  const int r0 = blockIdx.x * 128 + wv * 16 + quad * 4;
#pragma unroll
  for (int nt = 0; nt < NCOLS / 16; ++nt) {
    const int col = nt * 16 + l16;
    const float bv = biasS[col];
    float s = 0.f, s2 = 0.f;
#pragma unroll
    for (int i = 0; i < 4; ++i) {
      const int r = r0 + i;
      if (r < NN) {
        float v = acc[nt][i] + bv;
        if (EPI == 1) v = fmaxf(v, 0.0f);
        if (EPI == 2) {
          ((float*)Cptr)[(size_t)r * NCOLS + col] = v;
        } else {
          unsigned short us = f2b(v);
          ((unsigned short*)Cptr)[(size_t)r * NCOLS + col] = us;
          if (STATS) {
            float vr = b2f(us);  // stats on rounded value (matches gemm2's input)
            s += vr;
            s2 += vr * vr;
          }
        }
      }
    }
    if (STATS) {
      s += __shfl_xor(s, 16);
      s += __shfl_xor(s, 32);
      s2 += __shfl_xor(s2, 16);
      s2 += __shfl_xor(s2, 32);
      if (quad == 0) {
        atomicAdd(&sS[col], s);
        atomicAdd(&s2S[col], s2);
      }
    }
  }
  if (STATS) {
    __syncthreads();
    if (tid < NCOLS) {
      atomicAdd(&stats_out[tid], sS[tid]);
      atomicAdd(&stats_out[128 + tid], s2S[tid]);
    }
  }
}

// ---------- launch ----------
extern "C" void kernel_launch(void* const* d_in, const int* in_sizes, int n_in,
                              void* d_out, int out_size, void* d_ws, size_t ws_size,
                              hipStream_t stream) {
  const float* x = (const float*)d_in[0];
  const int* ei = (const int*)d_in[1];
  const float* W1 = (const float*)d_in[2];
  const float* b1 = (const float*)d_in[3];
  const float* g1 = (const float*)d_in[4];
  const float* be1 = (const float*)d_in[5];
  const float* W2 = (const float*)d_in[6];
  const float* b2 = (const float*)d_in[7];
  const float* fW1 = (const float*)d_in[8];
  const float* fb1 = (const float*)d_in[9];
  const float* fg1 = (const float*)d_in[10];
  const float* fbe1 = (const float*)d_in[11];
  const float* fW2 = (const float*)d_in[12];
  const float* fb2 = (const float*)d_in[13];

  char* ws = (char*)d_ws;
  unsigned short* x16 = (unsigned short*)ws;                       // 25.6 MB
  unsigned short* h16 = (unsigned short*)(ws + (size_t)25600000);  // 25.6 MB
  unsigned short* t16 = (unsigned short*)(ws + (size_t)51200000);  // 25.6 MB
  int2* buckets = (int2*)t16;  // 13.4 MB, consumed by scatter before t16 is written
  int* csr = (int*)(ws + (size_t)76800000);       // NN*CAP*4 = 22.4 MB
  int* cnt = (int*)(ws + (size_t)99200000);       // 400 KB
  float* stats = (float*)(ws + (size_t)99600000); // 4 KB: 4 layers x 256
  int* flag = (int*)(ws + (size_t)99604096);
  int* bcur = (int*)(ws + (size_t)99604224);      // 8 ints
  unsigned short* wt = (unsigned short*)(ws + (size_t)99605504);   // 262 KB

  const int vecBlocks = (NN * DD) / (256 * 8);  // 6250
  const int gemmBlocks = (NN + 127) / 128;      // 782
  const int edgeBlocks = NE / 256;              // 6250
  const int scatBlocks = SBLK * 8;              // 1024
  const int nodeBlocks = NN / 16;               // 6250

  detect_k<<<1, 64, 0, stream>>>(ei, flag, bcur);
  cast_k<<<vecBlocks, 256, 0, stream>>>(x, x16);
  pack_k<<<edgeBlocks, 256, 0, stream>>>(ei, buckets, bcur, cnt, stats, flag);
  wprep_k<<<480, 256, 0, stream>>>(W1, W2, fW1, fW2, wt);
  scatter_k<<<scatBlocks, 256, 0, stream>>>(buckets, bcur, cnt, csr);

  for (int l = 0; l < 3; ++l) {
    gather_k<<<nodeBlocks, 256, 0, stream>>>(cnt, csr, x16, h16);
    gemm_k<1, 128, 0, 1><<<gemmBlocks, 512, 0, stream>>>(
        h16, wt + (size_t)l * 16384, b1 + l * 128, nullptr, nullptr, nullptr,
        t16, stats + 256 * l);
    gemm_k<2, 128, 1, 0><<<gemmBlocks, 512, 0, stream>>>(
        t16, wt + (size_t)(3 + l) * 16384, b2 + l * 128, stats + 256 * l,
        g1 + l * 128, be1 + l * 128, x16, nullptr);
  }

  // final MLP: Linear -> BN -> ReLU -> Linear, out fp32 [NN x 64]
  gemm_k<1, 128, 0, 1><<<gemmBlocks, 512, 0, stream>>>(
      x16, wt + (size_t)6 * 16384, fb1, nullptr, nullptr, nullptr, t16,
      stats + 768);
  gemm_k<2, 64, 2, 0><<<gemmBlocks, 512, 0, stream>>>(
      t16, wt + (size_t)7 * 16384, fb2, stats + 768, fg1, fbe1, (float*)d_out,
      nullptr);
}

// Round 7
// 557.905 us; speedup vs baseline: 1.1907x; 1.1907x over previous
//
#include <hip/hip_runtime.h>

#define NN 100000
#define NE 1600000
#define DD 128
#define CAP 56      // padded-CSR capacity; P(Poisson(16) >= 56) ~ 5e-15
#define NGROUP 256  // edge-slice groups for filtered scatter

// ---------- bf16 helpers (manual, RNE) ----------
static __device__ __forceinline__ unsigned short f2b(float f) {
  unsigned int x = __float_as_uint(f);
  unsigned int r = x + 0x7fffu + ((x >> 16) & 1u);
  return (unsigned short)(r >> 16);
}
static __device__ __forceinline__ float b2f(unsigned short u) {
  return __uint_as_float(((unsigned int)u) << 16);
}

typedef __attribute__((ext_vector_type(8))) short short8;
typedef __attribute__((ext_vector_type(4))) float f32x4;

union V8 {
  uint4 u4;
  short8 s8;
  unsigned short us[8];
};

// ---------- edge-index dtype detector ----------
__global__ void detect_k(const int* __restrict__ ei, int* __restrict__ flag) {
  int v = ei[2 * threadIdx.x + 1];
  unsigned long long b = __ballot(v != 0);
  if (threadIdx.x == 0) *flag = (b == 0ull) ? 1 : 0;
}

// ---------- fp32 -> bf16 cast (x input, row-major) ----------
__global__ __launch_bounds__(256) void cast_k(const float* __restrict__ x,
                                              unsigned short* __restrict__ x16) {
  size_t i = ((size_t)blockIdx.x * 256 + threadIdx.x) * 8;
  f32x4 a = *(const f32x4*)(x + i);
  f32x4 b = *(const f32x4*)(x + i + 4);
  V8 v;
#pragma unroll
  for (int j = 0; j < 4; ++j) {
    v.us[j] = f2b(a[j]);
    v.us[4 + j] = f2b(b[j]);
  }
  *(uint4*)(x16 + i) = v.u4;
}

// ---------- pack edges to int2 (src,dst) + zero cnt + zero striped BN stat buffers ----------
__global__ __launch_bounds__(256) void pack_k(const int* __restrict__ ei,
                                              int2* __restrict__ packed,
                                              int* __restrict__ cnt,
                                              float* __restrict__ stats,
                                              const int* __restrict__ flag) {
  const int mode = *flag;
  const int gid = blockIdx.x * 256 + threadIdx.x;
  int s, d;
  if (mode) {  // int64 little-endian, values < 2^31: low word at even offset
    s = ((const int2*)ei)[gid].x;
    d = ((const int2*)ei)[(size_t)NE + gid].x;
  } else {
    s = ei[gid];
    d = ei[NE + gid];
  }
  packed[gid] = make_int2(s, d);
  if (gid < NN) cnt[gid] = 0;
  if (gid < 8192) stats[gid] = 0.f;  // 4 slots x 8 XCD stripes x 256
}

// ---------- padded-CSR scatter, XCD-range-filtered (R4-exact: proven 70 us) ----------
// R5 (nt-loads) and R6 (bucketing) both null/negative: scatter is bound by the
// 1.6M atomic-RMW + scattered-write machinery, not by its read traffic.
__global__ __launch_bounds__(256) void scatter_k(const int2* __restrict__ packed,
                                                 int* __restrict__ cnt,
                                                 int* __restrict__ csr) {
  const int r = blockIdx.x & 7;
  const int g = blockIdx.x >> 3;
  const int lo = r * (NN / 8), hi = lo + (NN / 8);
  for (int e = g * 256 + threadIdx.x; e < NE; e += NGROUP * 256) {
    int2 sd = packed[e];
    if (sd.y >= lo && sd.y < hi) {
      int c = atomicAdd(&cnt[sd.y], 1);
      if (c < CAP) csr[(size_t)sd.y * CAP + c] = sd.x;
    }
  }
}

// ---------- weight prep: transpose+cast all 7 matrices to bf16 wT[n][k] ----------
__global__ __launch_bounds__(256) void wprep_k(const float* __restrict__ W1,
                                               const float* __restrict__ W2,
                                               const float* __restrict__ fW1,
                                               const float* __restrict__ fW2,
                                               unsigned short* __restrict__ wt) {
  int b = blockIdx.x;
  const float* src;
  int moff, N;
  if (b < 192) {
    int m = b >> 6;
    src = W1 + m * 16384;
    moff = m * 16384;
    N = 128;
    b &= 63;
  } else if (b < 384) {
    int m = (b - 192) >> 6;
    src = W2 + m * 16384;
    moff = (3 + m) * 16384;
    N = 128;
    b = (b - 192) & 63;
  } else if (b < 448) {
    src = fW1;
    moff = 6 * 16384;
    N = 128;
    b -= 384;
  } else {
    src = fW2;
    moff = 7 * 16384;
    N = 64;
    b -= 448;
  }
  int idx = b * 256 + threadIdx.x;  // n*128 + k
  int n = idx >> 7, k = idx & 127;
  if (n < N) wt[moff + idx] = f2b(src[(size_t)k * N + n]);
}

// ---------- gather-reduce (unchanged control): h16[node] = x16[node] + sum x16[s] ----------
// 16 threads/node, 8 cols each; unroll-4 independent accumulators.
__global__ __launch_bounds__(256) void gather_k(const int* __restrict__ cnt,
                                                const int* __restrict__ csr,
                                                const unsigned short* __restrict__ x16,
                                                unsigned short* __restrict__ h16) {
  const int node = blockIdx.x * 16 + (threadIdx.x >> 4);
  const int l = threadIdx.x & 15;
  const int beg = node * CAP;
  const int end = beg + cnt[node];
  V8 v;
  v.u4 = *(const uint4*)(x16 + (size_t)node * DD + l * 8);
  float a0[8], a1[8], a2[8], a3[8];
#pragma unroll
  for (int j = 0; j < 8; ++j) {
    a0[j] = b2f(v.us[j]);
    a1[j] = 0.f;
    a2[j] = 0.f;
    a3[j] = 0.f;
  }
  int p = beg;
  for (; p + 4 <= end; p += 4) {
    const int s0 = csr[p], s1 = csr[p + 1], s2 = csr[p + 2], s3 = csr[p + 3];
    V8 w0, w1, w2, w3;
    w0.u4 = *(const uint4*)(x16 + (size_t)s0 * DD + l * 8);
    w1.u4 = *(const uint4*)(x16 + (size_t)s1 * DD + l * 8);
    w2.u4 = *(const uint4*)(x16 + (size_t)s2 * DD + l * 8);
    w3.u4 = *(const uint4*)(x16 + (size_t)s3 * DD + l * 8);
#pragma unroll
    for (int j = 0; j < 8; ++j) {
      a0[j] += b2f(w0.us[j]);
      a1[j] += b2f(w1.us[j]);
      a2[j] += b2f(w2.us[j]);
      a3[j] += b2f(w3.us[j]);
    }
  }
  for (; p < end; ++p) {
    const int s0 = csr[p];
    V8 w0;
    w0.u4 = *(const uint4*)(x16 + (size_t)s0 * DD + l * 8);
#pragma unroll
    for (int j = 0; j < 8; ++j) a0[j] += b2f(w0.us[j]);
  }
  V8 o;
#pragma unroll
  for (int j = 0; j < 8; ++j) o.us[j] = f2b((a0[j] + a1[j]) + (a2[j] + a3[j]));
  *(uint4*)(h16 + (size_t)node * DD + l * 8) = o.u4;
}

// ---------- MFMA GEMM: C[M x NCOLS] = A[M x 128] @ wT^T + bias ----------
// 512 threads / 128 rows per block; A-row loads hoisted above the LDS staging.
// R7: BN stats are XCD-STRIPED. Previously all 782 blocks atomicAdd'ed into
// one 1 KB buffer (16 cache lines shared by 8 XCDs) -> 200K contended
// device-scope RMWs (the same hotspot mechanism R6 exposed on bcur). Now
// block b accumulates into stripe b&7 (stats_out[(b&7)*256 + col]); the
// consumer sums the 8 stripes in its prologue.
// AMODE: 1 = A bf16 plain, 2 = A bf16 with BN(scale,shift from striped raw stats)+ReLU
// EPI:   0 = store bf16, 1 = relu + store bf16, 2 = store fp32
// STATS: 1 = accumulate per-column sum/sumsq of the (rounded) output
template <int AMODE, int NCOLS, int EPI, int STATS>
__global__ __launch_bounds__(512) void gemm_k(const unsigned short* __restrict__ Aptr,
                                              const unsigned short* __restrict__ wT,
                                              const float* __restrict__ bias,
                                              const float* __restrict__ bn_stats,
                                              const float* __restrict__ gamma,
                                              const float* __restrict__ beta,
                                              void* __restrict__ Cptr,
                                              float* __restrict__ stats_out) {
  __shared__ unsigned short bT[NCOLS][136];  // 136: 16B-aligned rows, bank-spread
  __shared__ float biasS[NCOLS];
  __shared__ float scS[128];
  __shared__ float shS[128];
  __shared__ float sS[NCOLS];
  __shared__ float s2S[NCOLS];
  const int tid = threadIdx.x;
  const int wv = tid >> 6;
  const int lane = tid & 63;
  const int l16 = lane & 15;
  const int quad = lane >> 4;
  const int arow = blockIdx.x * 128 + wv * 16 + l16;  // A row (m = lane&15)
  const bool rv = arow < NN;

  // ---- A loads first: latency overlaps the weight staging below ----
  V8 afr[4];
#pragma unroll
  for (int kc = 0; kc < 4; ++kc) {
    if (rv) {
      afr[kc].u4 = *(const uint4*)(Aptr + (size_t)arow * DD + kc * 32 + quad * 8);
    } else {
      afr[kc].u4 = make_uint4(0u, 0u, 0u, 0u);
    }
  }

  // prologue: straight vectorized copy of pre-transposed weights
  for (int i = tid; i < NCOLS * 16; i += 512) {
    int n = i >> 4, k8 = (i & 15) << 3;
    *(uint4*)&bT[n][k8] = *(const uint4*)(wT + n * 128 + k8);
  }
  if (tid < NCOLS) biasS[tid] = bias[tid];
  if (AMODE == 2 && tid < 128) {
    float su = 0.f, sq = 0.f;
#pragma unroll
    for (int j = 0; j < 8; ++j) {  // sum the 8 XCD stripes
      su += bn_stats[j * 256 + tid];
      sq += bn_stats[j * 256 + 128 + tid];
    }
    const float inv_n = 1.0f / (float)NN;
    float mu = su * inv_n;
    float var = sq * inv_n - mu * mu;
    float sc = gamma[tid] * rsqrtf(var + 1e-5f);
    scS[tid] = sc;
    shS[tid] = beta[tid] - mu * sc;
  }
  if (STATS && tid < NCOLS) {
    sS[tid] = 0.f;
    s2S[tid] = 0.f;
  }
  __syncthreads();

  f32x4 acc[NCOLS / 16];
#pragma unroll
  for (int nt = 0; nt < NCOLS / 16; ++nt) acc[nt] = (f32x4)(0.0f);

#pragma unroll
  for (int kc = 0; kc < 4; ++kc) {
    const int k0 = kc * 32 + quad * 8;
    V8 af = afr[kc];
    if (AMODE == 2) {
#pragma unroll
      for (int j = 0; j < 8; ++j) {
        float f = fmaf(b2f(af.us[j]), scS[k0 + j], shS[k0 + j]);
        af.us[j] = f2b(fmaxf(f, 0.0f));
      }
    }
#pragma unroll
    for (int nt = 0; nt < NCOLS / 16; ++nt) {
      V8 bf;
      bf.u4 = *(const uint4*)&bT[nt * 16 + l16][k0];
      acc[nt] = __builtin_amdgcn_mfma_f32_16x16x32_bf16(af.s8, bf.s8, acc[nt], 0, 0, 0);
    }
  }

  // C/D layout: col = lane&15, row = quad*4 + reg
  const int r0 = blockIdx.x * 128 + wv * 16 + quad * 4;
#pragma unroll
  for (int nt = 0; nt < NCOLS / 16; ++nt) {
    const int col = nt * 16 + l16;
    const float bv = biasS[col];
    float s = 0.f, s2 = 0.f;
#pragma unroll
    for (int i = 0; i < 4; ++i) {
      const int r = r0 + i;
      if (r < NN) {
        float v = acc[nt][i] + bv;
        if (EPI == 1) v = fmaxf(v, 0.0f);
        if (EPI == 2) {
          ((float*)Cptr)[(size_t)r * NCOLS + col] = v;
        } else {
          unsigned short us = f2b(v);
          ((unsigned short*)Cptr)[(size_t)r * NCOLS + col] = us;
          if (STATS) {
            float vr = b2f(us);  // stats on rounded value (matches gemm2's input)
            s += vr;
            s2 += vr * vr;
          }
        }
      }
    }
    if (STATS) {
      s += __shfl_xor(s, 16);
      s += __shfl_xor(s, 32);
      s2 += __shfl_xor(s2, 16);
      s2 += __shfl_xor(s2, 32);
      if (quad == 0) {
        atomicAdd(&sS[col], s);
        atomicAdd(&s2S[col], s2);
      }
    }
  }
  if (STATS) {
    __syncthreads();
    if (tid < NCOLS) {
      const int xs = (blockIdx.x & 7) * 256;  // XCD-local stripe
      atomicAdd(&stats_out[xs + tid], sS[tid]);
      atomicAdd(&stats_out[xs + 128 + tid], s2S[tid]);
    }
  }
}

// ---------- launch ----------
extern "C" void kernel_launch(void* const* d_in, const int* in_sizes, int n_in,
                              void* d_out, int out_size, void* d_ws, size_t ws_size,
                              hipStream_t stream) {
  const float* x = (const float*)d_in[0];
  const int* ei = (const int*)d_in[1];
  const float* W1 = (const float*)d_in[2];
  const float* b1 = (const float*)d_in[3];
  const float* g1 = (const float*)d_in[4];
  const float* be1 = (const float*)d_in[5];
  const float* W2 = (const float*)d_in[6];
  const float* b2 = (const float*)d_in[7];
  const float* fW1 = (const float*)d_in[8];
  const float* fb1 = (const float*)d_in[9];
  const float* fg1 = (const float*)d_in[10];
  const float* fbe1 = (const float*)d_in[11];
  const float* fW2 = (const float*)d_in[12];
  const float* fb2 = (const float*)d_in[13];

  char* ws = (char*)d_ws;
  unsigned short* x16 = (unsigned short*)ws;                       // 25.6 MB
  unsigned short* h16 = (unsigned short*)(ws + (size_t)25600000);  // 25.6 MB
  unsigned short* t16 = (unsigned short*)(ws + (size_t)51200000);  // 25.6 MB
  int2* packed = (int2*)t16;  // 12.8 MB, consumed by scatter before t16 is written
  int* csr = (int*)(ws + (size_t)76800000);       // NN*CAP*4 = 22.4 MB
  int* cnt = (int*)(ws + (size_t)99200000);       // 400 KB
  float* stats = (float*)(ws + (size_t)99600000); // 32 KB: 4 slots x 8 stripes x 256
  int* flag = (int*)(ws + (size_t)99632896);
  unsigned short* wt = (unsigned short*)(ws + (size_t)99634176);   // 262 KB

  const int vecBlocks = (NN * DD) / (256 * 8);  // 6250
  const int gemmBlocks = (NN + 127) / 128;      // 782
  const int edgeBlocks = NE / 256;              // 6250
  const int filtBlocks = NGROUP * 8;            // 2048
  const int nodeBlocks = NN / 16;               // 6250

  detect_k<<<1, 64, 0, stream>>>(ei, flag);
  cast_k<<<vecBlocks, 256, 0, stream>>>(x, x16);
  pack_k<<<edgeBlocks, 256, 0, stream>>>(ei, packed, cnt, stats, flag);
  wprep_k<<<480, 256, 0, stream>>>(W1, W2, fW1, fW2, wt);
  scatter_k<<<filtBlocks, 256, 0, stream>>>(packed, cnt, csr);

  for (int l = 0; l < 3; ++l) {
    gather_k<<<nodeBlocks, 256, 0, stream>>>(cnt, csr, x16, h16);
    gemm_k<1, 128, 0, 1><<<gemmBlocks, 512, 0, stream>>>(
        h16, wt + (size_t)l * 16384, b1 + l * 128, nullptr, nullptr, nullptr,
        t16, stats + 2048 * l);
    gemm_k<2, 128, 1, 0><<<gemmBlocks, 512, 0, stream>>>(
        t16, wt + (size_t)(3 + l) * 16384, b2 + l * 128, stats + 2048 * l,
        g1 + l * 128, be1 + l * 128, x16, nullptr);
  }

  // final MLP: Linear -> BN -> ReLU -> Linear, out fp32 [NN x 64]
  gemm_k<1, 128, 0, 1><<<gemmBlocks, 512, 0, stream>>>(
      x16, wt + (size_t)6 * 16384, fb1, nullptr, nullptr, nullptr, t16,
      stats + 6144);
  gemm_k<2, 64, 2, 0><<<gemmBlocks, 512, 0, stream>>>(
      t16, wt + (size_t)7 * 16384, fb2, stats + 6144, fg1, fbe1, (float*)d_out,
      nullptr);
}